// Round 7
// baseline (231.423 us; speedup 1.0000x reference)
//
#include <hip/hip_runtime.h>
#include <stdint.h>

#define NB   2
#define SS   2048
#define HIDN 1024
#define NHEAD 16
#define DKK  64

typedef __attribute__((ext_vector_type(8))) short bf16x8;
typedef __attribute__((ext_vector_type(4))) float f32x4;

__device__ __forceinline__ uint16_t f2bf(float f) {
    uint32_t u = __float_as_uint(f);
    u += 0x7FFF + ((u >> 16) & 1);
    return (uint16_t)(u >> 16);
}
// pack two fp32 -> packed bf16 pair (lo = f0)
__device__ __forceinline__ uint32_t pk2(float f0, float f1) {
    uint32_t u0 = __float_as_uint(f0);
    uint32_t u1 = __float_as_uint(f1);
    u0 += 0x7FFF + ((u0 >> 16) & 1);
    u1 += 0x7FFF + ((u1 >> 16) & 1);
    return (u0 >> 16) | (u1 & 0xFFFF0000u);
}
// single-instruction packed bf16 convert (RTNE)
__device__ __forceinline__ uint32_t cvtpk(float lo, float hi) {
    uint32_t r;
    asm("v_cvt_pk_bf16_f32 %0, %1, %2" : "=v"(r) : "v"(lo), "v"(hi));
    return r;
}
// bare v_exp_f32: computes 2^x (inputs pre-scaled by log2e)
__device__ __forceinline__ float exp2_fast(float x) {
    float r;
    asm("v_exp_f32 %0, %1" : "=v"(r) : "v"(x));
    return r;
}
// pack 8 consecutive fp32 * sc -> 8 bf16 (uint4)
__device__ __forceinline__ uint4 pack8(const float* __restrict__ s, float sc) {
    float4 a = *(const float4*)s;
    float4 b = *(const float4*)(s + 4);
    uint4 r;
    r.x = pk2(sc * a.x, sc * a.y);
    r.y = pk2(sc * a.z, sc * a.w);
    r.z = pk2(sc * b.x, sc * b.y);
    r.w = pk2(sc * b.z, sc * b.w);
    return r;
}
// async global->LDS, 16B/lane; LDS dest = wave-uniform base + lane*16
__device__ __forceinline__ void gl_lds16(const uint16_t* g, uint16_t* l) {
    __builtin_amdgcn_global_load_lds((const __attribute__((address_space(1))) void*)g,
                                     (__attribute__((address_space(3))) void*)l,
                                     16, 0, 0);
}

// ---- single fused conversion dispatch (HBM-bound) ----
__global__ __launch_bounds__(256, 4)
void cvt_all(const float* __restrict__ q, const float* __restrict__ k,
             const float* __restrict__ v, const float* __restrict__ bias,
             const float* __restrict__ w0, const float* __restrict__ w1,
             const float* __restrict__ w2, const float* __restrict__ w3,
             uint16_t* __restrict__ q16, uint16_t* __restrict__ k16,
             uint16_t* __restrict__ v16, uint16_t* __restrict__ w16o)
{
    int i = blockIdx.x * 256 + threadIdx.x;            // 0..1048575
    if (i < 524288) {                                  // q/k/v: 4M elems each
        size_t e = (size_t)i * 8;
        float sc = 1.0f + bias[i >> 7];
        *(uint4*)(q16 + e) = pack8(q + e, 1.0f);
        *(uint4*)(k16 + e) = pack8(k + e, sc);
        *(uint4*)(v16 + e) = pack8(v + e, sc);
    } else {                                           // 4 weight matrices
        int j = i - 524288;
        const float* src = (j < 131072) ? w0 : (j < 262144) ? w1
                         : (j < 393216) ? w2 : w3;
        size_t e = (size_t)(j & 131071) * 8;
        *(uint4*)(w16o + (size_t)(j >> 17) * 1048576 + e) = pack8(src + e, 1.0f);
    }
}

// ================= GEMM mainloop =================
// C[128,128] tile of A[4096,1024] @ W[1024,1024]^T. BK=64, DOUBLE-buffered
// global_load_lds: one barrier per K-iter; prefetch for it+1 issued right
// after the barrier so the vmcnt(0)-before-next-barrier drains loads that
// flew across the 32 MFMAs. XOR source-pre-swizzle:
// LDS[r][g] = glb[r][g^(r&7)]. 64 KB LDS, 4 waves, acc[4][4] (64x64/wave).
__device__ __forceinline__ void gemm_core(const uint16_t* __restrict__ A,
                                          const uint16_t* __restrict__ W,
                                          uint16_t* __restrict__ As0,
                                          uint16_t* __restrict__ As1,
                                          uint16_t* __restrict__ Bs0,
                                          uint16_t* __restrict__ Bs1,
                                          int m0, int n0,
                                          f32x4 acc[4][4])
{
    const int t    = threadIdx.x;
    const int w    = t >> 6;
    const int lane = t & 63;
    const int q    = lane >> 4;
    const int lr   = lane & 15;
    const int wr   = (w >> 1) * 64;
    const int wc   = (w & 1) * 64;
    const int srow = lane >> 3;
    const int sg   = (lane & 7) ^ srow;

    // preload tile 0 into buffer 0
#pragma unroll
    for (int c = 0; c < 4; ++c) {
        int r = w * 32 + c * 8;
        gl_lds16(A + (size_t)(m0 + r + srow) * HIDN + sg * 8, As0 + r * 64);
        gl_lds16(W + (size_t)(n0 + r + srow) * HIDN + sg * 8, Bs0 + r * 64);
    }

    for (int it = 0; it < 16; ++it) {
        uint16_t* Asc = (it & 1) ? As1 : As0;
        uint16_t* Bsc = (it & 1) ? Bs1 : Bs0;
        uint16_t* Asn = (it & 1) ? As0 : As1;
        uint16_t* Bsn = (it & 1) ? Bs0 : Bs1;
        __syncthreads();                 // drains DMA for tile it
        if (it + 1 < 16) {
            int k0 = (it + 1) * 64;
#pragma unroll
            for (int c = 0; c < 4; ++c) {
                int r = w * 32 + c * 8;
                gl_lds16(A + (size_t)(m0 + r + srow) * HIDN + k0 + sg * 8,
                         Asn + r * 64);
                gl_lds16(W + (size_t)(n0 + r + srow) * HIDN + k0 + sg * 8,
                         Bsn + r * 64);
            }
        }
        bf16x8 af[2][4], bfr[2][4];
#pragma unroll
        for (int s = 0; s < 2; ++s) {
#pragma unroll
            for (int i = 0; i < 4; ++i)
                af[s][i] = *(const bf16x8*)&Asc[(wr + i * 16 + lr) * 64 +
                                                (((s * 4 + q) ^ (lr & 7)) * 8)];
#pragma unroll
            for (int j = 0; j < 4; ++j)
                bfr[s][j] = *(const bf16x8*)&Bsc[(wc + j * 16 + lr) * 64 +
                                                 (((s * 4 + q) ^ (lr & 7)) * 8)];
        }
#pragma unroll
        for (int s = 0; s < 2; ++s)
#pragma unroll
            for (int i = 0; i < 4; ++i)
#pragma unroll
                for (int j = 0; j < 4; ++j)
                    acc[i][j] = __builtin_amdgcn_mfma_f32_16x16x32_bf16(
                        af[s][i], bfr[s][j], acc[i][j], 0, 0, 0);
    }
}

// fused Q/K/V projections: grid (8, 32, 3), XCD-swizzled (T1).
// Default dispatch puts the 8 consecutive-x blocks sharing one A-panel on 8
// DIFFERENT XCDs (panel fetched into 8 L2s). Bijective remap (nwg=768, %8==0)
// gives each XCD a contiguous 96-tile chunk -> same-panel blocks share L2.
__global__ __launch_bounds__(256, 2)
void gemm_qkv(const uint16_t* __restrict__ Qin, const uint16_t* __restrict__ Kin,
              const uint16_t* __restrict__ Vin, const uint16_t* __restrict__ W16,
              const float* __restrict__ bq, const float* __restrict__ bk,
              const float* __restrict__ bv,
              uint16_t* __restrict__ Qb, uint16_t* __restrict__ Kb,
              uint16_t* __restrict__ Vtb)
{
    __shared__ __align__(16) uint16_t As[2][128 * 64];
    __shared__ __align__(16) uint16_t Bs[2][128 * 64];

    const int bid = (blockIdx.z << 8) | (blockIdx.y << 3) | blockIdx.x;
    const int swz = (bid & 7) * 96 + (bid >> 3);       // nwg=768, cpx=96
    const int z   = swz >> 8;
    const int m0  = ((swz >> 3) & 31) * 128;
    const int n0  = (swz & 7) * 128;

    const uint16_t* A    = (z == 0) ? Qin : (z == 1) ? Kin : Vin;
    const uint16_t* W    = W16 + (size_t)z * 1048576;
    const float*    bias = (z == 0) ? bq : (z == 1) ? bk : bv;
    // fold 1/sqrt(64) AND log2(e) into Q so attention runs in exp2 domain
    const float     osc  = (z == 0) ? 0.125f * 1.44269504f : 1.0f;

    const int t    = threadIdx.x;
    const int w    = t >> 6;
    const int lane = t & 63;
    const int q    = lane >> 4;
    const int lr   = lane & 15;
    const int wr   = (w >> 1) * 64;
    const int wc   = (w & 1) * 64;

    f32x4 acc[4][4] = {};
    gemm_core(A, W, As[0], As[1], Bs[0], Bs[1], m0, n0, acc);

    if (z < 2) {
        // out bf16 [b][h][s][d]; C/D: col=lane&15, row=(lane>>4)*4+r
        uint16_t* o = (z == 0) ? Qb : Kb;
#pragma unroll
        for (int i = 0; i < 4; ++i)
#pragma unroll
            for (int j = 0; j < 4; ++j) {
                int gn = n0 + wc + j * 16 + lr;
                float bvx = bias[gn];
#pragma unroll
                for (int r = 0; r < 4; ++r) {
                    int row = m0 + wr + i * 16 + q * 4 + r;
                    int b = row >> 11, s = row & 2047;
                    size_t dst = (size_t)b * (NHEAD * SS * DKK)
                               + (size_t)(gn >> 6) * (SS * DKK)
                               + (size_t)s * DKK + (gn & 63);
                    o[dst] = f2bf((acc[i][j][r] + bvx) * osc);
                }
            }
    } else {
        // V^T: N-tile spans 2 heads -> two-pass transpose via LDS.
        // Mainloop no longer ends on a barrier: sync before reusing LDS.
        __syncthreads();
        uint16_t* Tr = As[0];                          // 64*136 = 17.4 KB
        int b = m0 >> 11;
#pragma unroll
        for (int hh = 0; hh < 2; ++hh) {
            if ((w & 1) == hh) {
#pragma unroll
                for (int j = 0; j < 4; ++j) {
                    int dl = j * 16 + lr;
                    float bvx = bias[n0 + hh * 64 + dl];
#pragma unroll
                    for (int r = 0; r < 4; ++r) {
                        int sl = wr + (q * 4 + r);
                        Tr[dl * 136 + sl +  0] = f2bf(acc[0][j][r] + bvx);
                        Tr[dl * 136 + sl + 16] = f2bf(acc[1][j][r] + bvx);
                        Tr[dl * 136 + sl + 32] = f2bf(acc[2][j][r] + bvx);
                        Tr[dl * 136 + sl + 48] = f2bf(acc[3][j][r] + bvx);
                    }
                }
            }
            __syncthreads();
            int hgl = (n0 >> 6) + hh;
#pragma unroll
            for (int p = 0; p < 4; ++p) {
                int idx = p * 256 + t;
                int d   = idx >> 4;
                int sc8 = (idx & 15) * 8;
                size_t dst = ((size_t)(b * NHEAD + hgl) * DKK + d) * SS
                           + (m0 & 2047) + sc8;
                *(uint4*)&Vtb[dst] = *(const uint4*)&Tr[d * 136 + sc8];
            }
            __syncthreads();
        }
    }
}

// final projection: A bf16 (Xb), out fp32 d_out. grid (8, 32), XCD-swizzled.
__global__ __launch_bounds__(256, 2)
void gemm_out(const uint16_t* __restrict__ Xb, const uint16_t* __restrict__ W,
              const float* __restrict__ bias, float* __restrict__ out)
{
    __shared__ __align__(16) uint16_t As[2][128 * 64];
    __shared__ __align__(16) uint16_t Bs[2][128 * 64];

    const int bid = (blockIdx.y << 3) | blockIdx.x;
    const int swz = (bid & 7) * 32 + (bid >> 3);       // nwg=256, cpx=32
    const int m0  = (swz >> 3) * 128;
    const int n0  = (swz & 7) * 128;

    const int t    = threadIdx.x;
    const int w    = t >> 6;
    const int lane = t & 63;
    const int q    = lane >> 4;
    const int lr   = lane & 15;
    const int wr   = (w >> 1) * 64;
    const int wc   = (w & 1) * 64;

    f32x4 acc[4][4] = {};
    gemm_core(Xb, W, As[0], As[1], Bs[0], Bs[1], m0, n0, acc);

#pragma unroll
    for (int i = 0; i < 4; ++i)
#pragma unroll
        for (int j = 0; j < 4; ++j) {
            int gn = n0 + wc + j * 16 + lr;
            float bvx = bias[gn];
#pragma unroll
            for (int r = 0; r < 4; ++r) {
                int row = m0 + wr + i * 16 + q * 4 + r;
                out[(size_t)row * HIDN + gn] = acc[i][j][r] + bvx;
            }
        }
}

// ---- flash attention, S^T formulation, exp2 domain, XOR-swizzled LDS ----
// 512 thr = 8 waves x 16 q-rows. XCD-swizzled grid (T1): same-head blocks
// (shared 256KB K/V) cluster on one XCD's L2. All LDS unpadded stride-64
// with XOR swizzle col_group ^= (row&7) (T2, round-6 verified: conflicts
// 1.16e7 -> 2.1e6). lst kept as PER-LANE partial; quad-reduction deferred
// to the epilogue (saves 2 shfl_xor per tile; alpha is quad-uniform after
// the rmax shuffles so the deferral is exact).
// Q pre-scaled (1/8)*log2e. Per-lane: one q-row (lr), 16 keys (ni*16+q*4+r).
// P round-trips wave-private LDS rows. K/V tiles reg-prefetched (1 uint4
// each per thread, no spill). Defer-max: skip rescale unless growth > 11.5.
// Q,K: [B,NH,S,64] bf16; Vt: [B,NH,64,S] bf16; X: [B,S,1024] bf16
__global__ __launch_bounds__(512, 4)
void flash_attn(const uint16_t* __restrict__ Qg, const uint16_t* __restrict__ Kg,
                const uint16_t* __restrict__ Vtg, const int* __restrict__ mask,
                uint16_t* __restrict__ X)
{
    __shared__ __align__(16) uint16_t QP[128 * 64];   // Q, then per-wave P rows
    __shared__ __align__(16) uint16_t Ks[64 * 64];
    __shared__ __align__(16) uint16_t Vs[64 * 64];    // V^T tile [d][key]
    __shared__ __align__(16) float Amf[SS];           // additive mask (log2 dom)

    const int t    = threadIdx.x;
    const int w    = t >> 6;
    const int lane = t & 63;
    const int q    = lane >> 4;
    const int lr   = lane & 15;

    const int bid = (blockIdx.y << 4) | blockIdx.x;
    const int swz = (bid & 7) * 64 + (bid >> 3);       // nwg=512, cpx=64
    const int bh  = swz >> 4;
    const int q0  = (swz & 15) * 128;

    const int b    = bh >> 4;
    const int h    = bh & 15;
    const size_t head = (size_t)bh * SS * DKK;

#pragma unroll
    for (int p = 0; p < 2; ++p) {
        int idx = p * 512 + t;
        int row = idx >> 3;
        int g   = idx & 7;
        *(uint4*)&QP[row * 64 + ((g ^ (row & 7)) * 8)] =
            *(const uint4*)(Qg + head + (size_t)(q0 + row) * DKK + g * 8);
    }
#pragma unroll
    for (int p = 0; p < 4; ++p) {
        int i = p * 512 + t;
        Amf[i] = (mask[b * SS + i] == 0) ? -14426.95f : 0.0f;
    }

    // prefetch K/V tile 0 into registers while Q staging settles
    const int srow = t >> 3;
    const int sgf  = t & 7;                           // global col-group
    const int scol = sgf * 8;
    const int swzc = (sgf ^ (srow & 7)) * 8;          // swizzled LDS col
    uint4 kreg = *(const uint4*)(Kg + head + (size_t)srow * DKK + scol);
    uint4 vreg = *(const uint4*)(Vtg + head + (size_t)srow * SS + scol);

    __syncthreads();

    // Q as B-operand: B[k=group*8+j][n=lane&15] = Q[n][k], swizzled read
    bf16x8 qf[2];
#pragma unroll
    for (int s = 0; s < 2; ++s)
        qf[s] = *(const bf16x8*)&QP[(w * 16 + lr) * 64 +
                                    (((s * 4 + q) ^ (lr & 7)) * 8)];

    float mst = -1e30f, lst = 0.0f;                   // lst = per-lane partial
    f32x4 oacc[4] = {};

    for (int kv0 = 0; kv0 < SS; kv0 += 64) {
        // write the prefetched tile (compiler inserts the vmcnt drain)
        *(uint4*)&Ks[srow * 64 + swzc] = kreg;
        *(uint4*)&Vs[srow * 64 + swzc] = vreg;
        __syncthreads();

        // issue next tile's loads now; latency hides under QK/softmax/PV
        if (kv0 + 64 < SS) {
            kreg = *(const uint4*)(Kg + head + (size_t)(kv0 + 64 + srow) * DKK + scol);
            vreg = *(const uint4*)(Vtg + head + (size_t)srow * SS + kv0 + 64 + scol);
        }

        // S^T[key][q] = K · Q^T : A = K rows (swizzled read), B = Q
        f32x4 st[4];
#pragma unroll
        for (int ni = 0; ni < 4; ++ni) {
            bf16x8 kf0 = *(const bf16x8*)&Ks[(ni * 16 + lr) * 64 +
                                             ((q ^ (lr & 7)) * 8)];
            bf16x8 kf1 = *(const bf16x8*)&Ks[(ni * 16 + lr) * 64 +
                                             (((4 + q) ^ (lr & 7)) * 8)];
            f32x4 z = {0.0f, 0.0f, 0.0f, 0.0f};
            z = __builtin_amdgcn_mfma_f32_16x16x32_bf16(kf0, qf[0], z, 0, 0, 0);
            z = __builtin_amdgcn_mfma_f32_16x16x32_bf16(kf1, qf[1], z, 0, 0, 0);
            st[ni] = z;
        }

        // additive mask + in-lane row max (lane owns 16 keys of q-row lr)
        float rmax = -1e30f;
#pragma unroll
        for (int ni = 0; ni < 4; ++ni) {
            float4 am = *(const float4*)&Amf[kv0 + ni * 16 + q * 4];
            st[ni][0] += am.x; st[ni][1] += am.y;
            st[ni][2] += am.z; st[ni][3] += am.w;
#pragma unroll
            for (int r = 0; r < 4; ++r) rmax = fmaxf(rmax, st[ni][r]);
        }
        rmax = fmaxf(rmax, __shfl_xor(rmax, 16));
        rmax = fmaxf(rmax, __shfl_xor(rmax, 32));

        // defer-max: only rescale when some row in the wave grew materially
        if (__any(rmax > mst + 11.5f)) {
            float mnew  = fmaxf(mst, rmax);
            float alpha = exp2_fast(mst - mnew);      // quad-uniform per row
            mst = mnew;
            lst *= alpha;
#pragma unroll
            for (int dj = 0; dj < 4; ++dj) {
                oacc[dj][0] *= alpha; oacc[dj][1] *= alpha;
                oacc[dj][2] *= alpha; oacc[dj][3] *= alpha;
            }
        }

        // P: logical elems [ni*16+q*4 .. +3] of row (w*16+lr); group
        // g = ni*2+(q>>1), sub-offset (q&1)*4; physical col (g^(lr&7))*8.
        float rsum = 0.0f;
#pragma unroll
        for (int ni = 0; ni < 4; ++ni) {
            float p0 = exp2_fast(st[ni][0] - mst);
            float p1 = exp2_fast(st[ni][1] - mst);
            float p2 = exp2_fast(st[ni][2] - mst);
            float p3 = exp2_fast(st[ni][3] - mst);
            rsum += (p0 + p1) + (p2 + p3);
            uint2 pw = make_uint2(cvtpk(p0, p1), cvtpk(p2, p3));
            *(uint2*)&QP[(w * 16 + lr) * 64 +
                         (((ni * 2 + (q >> 1)) ^ (lr & 7)) * 8) + (q & 1) * 4] = pw;
        }
        lst += rsum;                                  // lane-local; reduce later

        // O^T[d][q] += V^T · P^T  (wave-private P rows; DS in-order, no barrier)
#pragma unroll
        for (int ks = 0; ks < 2; ++ks) {
            bf16x8 pfB = *(const bf16x8*)&QP[(w * 16 + lr) * 64 +
                                             (((ks * 4 + q) ^ (lr & 7)) * 8)];
#pragma unroll
            for (int dj = 0; dj < 4; ++dj) {
                bf16x8 vfA = *(const bf16x8*)&Vs[(dj * 16 + lr) * 64 +
                                                 (((ks * 4 + q) ^ (lr & 7)) * 8)];
                oacc[dj] = __builtin_amdgcn_mfma_f32_16x16x32_bf16(vfA, pfB, oacc[dj], 0, 0, 0);
            }
        }
        __syncthreads();   // Ks/Vs free for next tile
    }

    // epilogue: reduce per-lane lst across the 4 quads of this q-row, then
    // O^T lane holds d = dj*16+q*4+r for q-row s = q0+w*16+lr
    {
        lst += __shfl_xor(lst, 16);
        lst += __shfl_xor(lst, 32);
        float inv = 1.0f / lst;
        int s = q0 + w * 16 + lr;
        uint16_t* xp = X + (size_t)(b * SS + s) * HIDN + h * DKK;
#pragma unroll
        for (int dj = 0; dj < 4; ++dj) {
            uint2 pw = make_uint2(cvtpk(oacc[dj][0] * inv, oacc[dj][1] * inv),
                                  cvtpk(oacc[dj][2] * inv, oacc[dj][3] * inv));
            *(uint2*)(xp + dj * 16 + q * 4) = pw;
        }
    }
}

extern "C" void kernel_launch(void* const* d_in, const int* in_sizes, int n_in,
                              void* d_out, int out_size, void* d_ws, size_t ws_size,
                              hipStream_t stream) {
    const float* query = (const float*)d_in[0];
    const float* key   = (const float*)d_in[1];
    const float* value = (const float*)d_in[2];
    const float* bias  = (const float*)d_in[3];
    const int*   mask  = (const int*)d_in[4];
    const float* wq = (const float*)d_in[5];
    const float* bq = (const float*)d_in[6];
    const float* wk = (const float*)d_in[7];
    const float* bk = (const float*)d_in[8];
    const float* wv = (const float*)d_in[9];
    const float* bv = (const float*)d_in[10];
    const float* wo = (const float*)d_in[11];
    const float* bo = (const float*)d_in[12];

    const size_t TEN = (size_t)NB * SS * HIDN;       // 4,194,304
    uint16_t* Qin = (uint16_t*)d_ws;                 // 0
    uint16_t* Kin = Qin + TEN;                       // 4M
    uint16_t* Vin = Kin + TEN;                       // 8M
    uint16_t* W16 = Vin + TEN;                       // 12M (4 x 1M: wq,wk,wv,wo)
    uint16_t* Qb  = W16 + 4 * 1048576;               // 16M
    uint16_t* Kb  = Qb + TEN;                        // 20M
    uint16_t* Vtb = Kb + TEN;                        // 24M (56 MB total)
    uint16_t* Xb  = Qin;                             // Qin dead after gemm_qkv

    cvt_all<<<4096, 256, 0, stream>>>(query, key, value, bias,
                                      wq, wk, wv, wo, Qin, Kin, Vin, W16);
    gemm_qkv<<<dim3(8, 32, 3), 256, 0, stream>>>(Qin, Kin, Vin, W16,
                                                 bq, bk, bv, Qb, Kb, Vtb);
    flash_attn<<<dim3(SS / 128, NB * NHEAD), 512, 0, stream>>>(Qb, Kb, Vtb, mask, Xb);
    gemm_out<<<dim3(8, 32), 256, 0, stream>>>(Xb, W16 + 3 * 1048576, bo, (float*)d_out);
}

// Round 8
// 227.367 us; speedup vs baseline: 1.0178x; 1.0178x over previous
//
#include <hip/hip_runtime.h>
#include <stdint.h>

#define NB   2
#define SS   2048
#define HIDN 1024
#define NHEAD 16
#define DKK  64

typedef __attribute__((ext_vector_type(8))) short bf16x8;
typedef __attribute__((ext_vector_type(4))) float f32x4;

__device__ __forceinline__ uint16_t f2bf(float f) {
    uint32_t u = __float_as_uint(f);
    u += 0x7FFF + ((u >> 16) & 1);
    return (uint16_t)(u >> 16);
}
// pack two fp32 -> packed bf16 pair (lo = f0)
__device__ __forceinline__ uint32_t pk2(float f0, float f1) {
    uint32_t u0 = __float_as_uint(f0);
    uint32_t u1 = __float_as_uint(f1);
    u0 += 0x7FFF + ((u0 >> 16) & 1);
    u1 += 0x7FFF + ((u1 >> 16) & 1);
    return (u0 >> 16) | (u1 & 0xFFFF0000u);
}
// single-instruction packed bf16 convert (RTNE)
__device__ __forceinline__ uint32_t cvtpk(float lo, float hi) {
    uint32_t r;
    asm("v_cvt_pk_bf16_f32 %0, %1, %2" : "=v"(r) : "v"(lo), "v"(hi));
    return r;
}
// bare v_exp_f32: computes 2^x (inputs pre-scaled by log2e)
__device__ __forceinline__ float exp2_fast(float x) {
    float r;
    asm("v_exp_f32 %0, %1" : "=v"(r) : "v"(x));
    return r;
}
// pack 8 consecutive fp32 * sc -> 8 bf16 (uint4)
__device__ __forceinline__ uint4 pack8(const float* __restrict__ s, float sc) {
    float4 a = *(const float4*)s;
    float4 b = *(const float4*)(s + 4);
    uint4 r;
    r.x = pk2(sc * a.x, sc * a.y);
    r.y = pk2(sc * a.z, sc * a.w);
    r.z = pk2(sc * b.x, sc * b.y);
    r.w = pk2(sc * b.z, sc * b.w);
    return r;
}
// async global->LDS, 16B/lane; LDS dest = wave-uniform base + lane*16
__device__ __forceinline__ void gl_lds16(const uint16_t* g, uint16_t* l) {
    __builtin_amdgcn_global_load_lds((const __attribute__((address_space(1))) void*)g,
                                     (__attribute__((address_space(3))) void*)l,
                                     16, 0, 0);
}

// ---- single fused conversion dispatch (HBM-bound) ----
__global__ __launch_bounds__(256, 4)
void cvt_all(const float* __restrict__ q, const float* __restrict__ k,
             const float* __restrict__ v, const float* __restrict__ bias,
             const float* __restrict__ w0, const float* __restrict__ w1,
             const float* __restrict__ w2, const float* __restrict__ w3,
             uint16_t* __restrict__ q16, uint16_t* __restrict__ k16,
             uint16_t* __restrict__ v16, uint16_t* __restrict__ w16o)
{
    int i = blockIdx.x * 256 + threadIdx.x;            // 0..1048575
    if (i < 524288) {                                  // q/k/v: 4M elems each
        size_t e = (size_t)i * 8;
        float sc = 1.0f + bias[i >> 7];
        *(uint4*)(q16 + e) = pack8(q + e, 1.0f);
        *(uint4*)(k16 + e) = pack8(k + e, sc);
        *(uint4*)(v16 + e) = pack8(v + e, sc);
    } else {                                           // 4 weight matrices
        int j = i - 524288;
        const float* src = (j < 131072) ? w0 : (j < 262144) ? w1
                         : (j < 393216) ? w2 : w3;
        size_t e = (size_t)(j & 131071) * 8;
        *(uint4*)(w16o + (size_t)(j >> 17) * 1048576 + e) = pack8(src + e, 1.0f);
    }
}

// ================= GEMM mainloop (m97 replica, pressure-controlled) =======
// C[128,128] tile of A[4096,1024] @ W[1024,1024]^T. BK=64, SINGLE-buffered
// 32 KB LDS, 2 barriers/K-step -- the verified m97 structure whose 874 TF
// relies on 3-4 blocks/CU implicit wave overlap (m114). Occupancy is
// protected by SPLIT-S fragment loading: only 8 frags (32 VGPR) live at a
// time instead of 16 (64 VGPR), so natural allocation fits >=3 waves/SIMD
// without spilling (the suspected invariant defect of rounds 5-7: either
// spill at (256,3) or 2 blocks/CU at (256,2), both ~flat).
// XOR source-pre-swizzle: LDS[r][g] = glb[r][g^(r&7)].
__device__ __forceinline__ void gemm_core(const uint16_t* __restrict__ A,
                                          const uint16_t* __restrict__ W,
                                          uint16_t* __restrict__ As,
                                          uint16_t* __restrict__ Bs,
                                          int m0, int n0,
                                          f32x4 acc[4][4])
{
    const int t    = threadIdx.x;
    const int w    = t >> 6;
    const int lane = t & 63;
    const int q    = lane >> 4;
    const int lr   = lane & 15;
    const int wr   = (w >> 1) * 64;
    const int wc   = (w & 1) * 64;
    const int srow = lane >> 3;
    const int sg   = (lane & 7) ^ srow;

    for (int it = 0; it < 16; ++it) {
        const int k0 = it * 64;
        // stage tile it (A: 128x64, B: 128x64)
#pragma unroll
        for (int c = 0; c < 4; ++c) {
            int r = w * 32 + c * 8;
            gl_lds16(A + (size_t)(m0 + r + srow) * HIDN + k0 + sg * 8,
                     As + r * 64);
            gl_lds16(W + (size_t)(n0 + r + srow) * HIDN + k0 + sg * 8,
                     Bs + r * 64);
        }
        __syncthreads();   // compiler drains vmcnt(0) before barrier

#pragma unroll
        for (int s = 0; s < 2; ++s) {
            // frags declared inside the s-scope: short live range, low VGPR
            bf16x8 af[4], bfr[4];
#pragma unroll
            for (int i = 0; i < 4; ++i)
                af[i] = *(const bf16x8*)&As[(wr + i * 16 + lr) * 64 +
                                            (((s * 4 + q) ^ (lr & 7)) * 8)];
#pragma unroll
            for (int j = 0; j < 4; ++j)
                bfr[j] = *(const bf16x8*)&Bs[(wc + j * 16 + lr) * 64 +
                                             (((s * 4 + q) ^ (lr & 7)) * 8)];
#pragma unroll
            for (int i = 0; i < 4; ++i)
#pragma unroll
                for (int j = 0; j < 4; ++j)
                    acc[i][j] = __builtin_amdgcn_mfma_f32_16x16x32_bf16(
                        af[i], bfr[j], acc[i][j], 0, 0, 0);
        }
        __syncthreads();   // LDS free for next K-step's staging
    }
}

// fused Q/K/V projections: grid (8, 32, 3), XCD-swizzled (T1, bijective).
__global__ __launch_bounds__(256, 3)
void gemm_qkv(const uint16_t* __restrict__ Qin, const uint16_t* __restrict__ Kin,
              const uint16_t* __restrict__ Vin, const uint16_t* __restrict__ W16,
              const float* __restrict__ bq, const float* __restrict__ bk,
              const float* __restrict__ bv,
              uint16_t* __restrict__ Qb, uint16_t* __restrict__ Kb,
              uint16_t* __restrict__ Vtb)
{
    __shared__ __align__(16) uint16_t Sh[2 * 128 * 64];   // As | Bs (32 KB)
    uint16_t* As = Sh;
    uint16_t* Bs = Sh + 128 * 64;

    const int bid = (blockIdx.z << 8) | (blockIdx.y << 3) | blockIdx.x;
    const int swz = (bid & 7) * 96 + (bid >> 3);       // nwg=768, cpx=96
    const int z   = swz >> 8;
    const int m0  = ((swz >> 3) & 31) * 128;
    const int n0  = (swz & 7) * 128;

    const uint16_t* A    = (z == 0) ? Qin : (z == 1) ? Kin : Vin;
    const uint16_t* W    = W16 + (size_t)z * 1048576;
    const float*    bias = (z == 0) ? bq : (z == 1) ? bk : bv;
    // fold 1/sqrt(64) AND log2(e) into Q so attention runs in exp2 domain
    const float     osc  = (z == 0) ? 0.125f * 1.44269504f : 1.0f;

    const int t    = threadIdx.x;
    const int w    = t >> 6;
    const int lane = t & 63;
    const int q    = lane >> 4;
    const int lr   = lane & 15;
    const int wr   = (w >> 1) * 64;
    const int wc   = (w & 1) * 64;

    f32x4 acc[4][4] = {};
    gemm_core(A, W, As, Bs, m0, n0, acc);

    if (z < 2) {
        // out bf16 [b][h][s][d]; C/D: col=lane&15, row=(lane>>4)*4+r
        uint16_t* o = (z == 0) ? Qb : Kb;
#pragma unroll
        for (int i = 0; i < 4; ++i)
#pragma unroll
            for (int j = 0; j < 4; ++j) {
                int gn = n0 + wc + j * 16 + lr;
                float bvx = bias[gn];
#pragma unroll
                for (int r = 0; r < 4; ++r) {
                    int row = m0 + wr + i * 16 + q * 4 + r;
                    int b = row >> 11, s = row & 2047;
                    size_t dst = (size_t)b * (NHEAD * SS * DKK)
                               + (size_t)(gn >> 6) * (SS * DKK)
                               + (size_t)s * DKK + (gn & 63);
                    o[dst] = f2bf((acc[i][j][r] + bvx) * osc);
                }
            }
    } else {
        // V^T: N-tile spans 2 heads -> two-pass transpose via LDS.
        // Core ends on a barrier; Sh (32 KB) is free, Tr needs 17.4 KB.
        uint16_t* Tr = Sh;
        int b = m0 >> 11;
#pragma unroll
        for (int hh = 0; hh < 2; ++hh) {
            if ((w & 1) == hh) {
#pragma unroll
                for (int j = 0; j < 4; ++j) {
                    int dl = j * 16 + lr;
                    float bvx = bias[n0 + hh * 64 + dl];
#pragma unroll
                    for (int r = 0; r < 4; ++r) {
                        int sl = wr + (q * 4 + r);
                        Tr[dl * 136 + sl +  0] = f2bf(acc[0][j][r] + bvx);
                        Tr[dl * 136 + sl + 16] = f2bf(acc[1][j][r] + bvx);
                        Tr[dl * 136 + sl + 32] = f2bf(acc[2][j][r] + bvx);
                        Tr[dl * 136 + sl + 48] = f2bf(acc[3][j][r] + bvx);
                    }
                }
            }
            __syncthreads();
            int hgl = (n0 >> 6) + hh;
#pragma unroll
            for (int p = 0; p < 4; ++p) {
                int idx = p * 256 + t;
                int d   = idx >> 4;
                int sc8 = (idx & 15) * 8;
                size_t dst = ((size_t)(b * NHEAD + hgl) * DKK + d) * SS
                           + (m0 & 2047) + sc8;
                *(uint4*)&Vtb[dst] = *(const uint4*)&Tr[d * 136 + sc8];
            }
            __syncthreads();
        }
    }
}

// final projection: A bf16 (Xb), out fp32 d_out. grid (8, 32), XCD-swizzled.
__global__ __launch_bounds__(256, 3)
void gemm_out(const uint16_t* __restrict__ Xb, const uint16_t* __restrict__ W,
              const float* __restrict__ bias, float* __restrict__ out)
{
    __shared__ __align__(16) uint16_t Sh[2 * 128 * 64];
    uint16_t* As = Sh;
    uint16_t* Bs = Sh + 128 * 64;

    const int bid = (blockIdx.y << 3) | blockIdx.x;
    const int swz = (bid & 7) * 32 + (bid >> 3);       // nwg=256, cpx=32
    const int m0  = (swz >> 3) * 128;
    const int n0  = (swz & 7) * 128;

    const int t    = threadIdx.x;
    const int w    = t >> 6;
    const int lane = t & 63;
    const int q    = lane >> 4;
    const int lr   = lane & 15;
    const int wr   = (w >> 1) * 64;
    const int wc   = (w & 1) * 64;

    f32x4 acc[4][4] = {};
    gemm_core(Xb, W, As, Bs, m0, n0, acc);

#pragma unroll
    for (int i = 0; i < 4; ++i)
#pragma unroll
        for (int j = 0; j < 4; ++j) {
            int gn = n0 + wc + j * 16 + lr;
            float bvx = bias[gn];
#pragma unroll
            for (int r = 0; r < 4; ++r) {
                int row = m0 + wr + i * 16 + q * 4 + r;
                out[(size_t)row * HIDN + gn] = acc[i][j][r] + bvx;
            }
        }
}

// ---- flash attention (round-7 control: UNCHANGED) ----
// 512 thr = 8 waves x 16 q-rows. XCD-swizzled grid (T1). LDS unpadded
// stride-64 XOR swizzle (T2). Per-lane lst partial, epilogue reduce.
// Q pre-scaled (1/8)*log2e; exp2 domain; defer-max THR 11.5.
// Q,K: [B,NH,S,64] bf16; Vt: [B,NH,64,S] bf16; X: [B,S,1024] bf16
__global__ __launch_bounds__(512, 4)
void flash_attn(const uint16_t* __restrict__ Qg, const uint16_t* __restrict__ Kg,
                const uint16_t* __restrict__ Vtg, const int* __restrict__ mask,
                uint16_t* __restrict__ X)
{
    __shared__ __align__(16) uint16_t QP[128 * 64];   // Q, then per-wave P rows
    __shared__ __align__(16) uint16_t Ks[64 * 64];
    __shared__ __align__(16) uint16_t Vs[64 * 64];    // V^T tile [d][key]
    __shared__ __align__(16) float Amf[SS];           // additive mask (log2 dom)

    const int t    = threadIdx.x;
    const int w    = t >> 6;
    const int lane = t & 63;
    const int q    = lane >> 4;
    const int lr   = lane & 15;

    const int bid = (blockIdx.y << 4) | blockIdx.x;
    const int swz = (bid & 7) * 64 + (bid >> 3);       // nwg=512, cpx=64
    const int bh  = swz >> 4;
    const int q0  = (swz & 15) * 128;

    const int b    = bh >> 4;
    const int h    = bh & 15;
    const size_t head = (size_t)bh * SS * DKK;

#pragma unroll
    for (int p = 0; p < 2; ++p) {
        int idx = p * 512 + t;
        int row = idx >> 3;
        int g   = idx & 7;
        *(uint4*)&QP[row * 64 + ((g ^ (row & 7)) * 8)] =
            *(const uint4*)(Qg + head + (size_t)(q0 + row) * DKK + g * 8);
    }
#pragma unroll
    for (int p = 0; p < 4; ++p) {
        int i = p * 512 + t;
        Amf[i] = (mask[b * SS + i] == 0) ? -14426.95f : 0.0f;
    }

    // prefetch K/V tile 0 into registers while Q staging settles
    const int srow = t >> 3;
    const int sgf  = t & 7;                           // global col-group
    const int scol = sgf * 8;
    const int swzc = (sgf ^ (srow & 7)) * 8;          // swizzled LDS col
    uint4 kreg = *(const uint4*)(Kg + head + (size_t)srow * DKK + scol);
    uint4 vreg = *(const uint4*)(Vtg + head + (size_t)srow * SS + scol);

    __syncthreads();

    // Q as B-operand: B[k=group*8+j][n=lane&15] = Q[n][k], swizzled read
    bf16x8 qf[2];
#pragma unroll
    for (int s = 0; s < 2; ++s)
        qf[s] = *(const bf16x8*)&QP[(w * 16 + lr) * 64 +
                                    (((s * 4 + q) ^ (lr & 7)) * 8)];

    float mst = -1e30f, lst = 0.0f;                   // lst = per-lane partial
    f32x4 oacc[4] = {};

    for (int kv0 = 0; kv0 < SS; kv0 += 64) {
        // write the prefetched tile (compiler inserts the vmcnt drain)
        *(uint4*)&Ks[srow * 64 + swzc] = kreg;
        *(uint4*)&Vs[srow * 64 + swzc] = vreg;
        __syncthreads();

        // issue next tile's loads now; latency hides under QK/softmax/PV
        if (kv0 + 64 < SS) {
            kreg = *(const uint4*)(Kg + head + (size_t)(kv0 + 64 + srow) * DKK + scol);
            vreg = *(const uint4*)(Vtg + head + (size_t)srow * SS + kv0 + 64 + scol);
        }

        // S^T[key][q] = K · Q^T : A = K rows (swizzled read), B = Q
        f32x4 st[4];
#pragma unroll
        for (int ni = 0; ni < 4; ++ni) {
            bf16x8 kf0 = *(const bf16x8*)&Ks[(ni * 16 + lr) * 64 +
                                             ((q ^ (lr & 7)) * 8)];
            bf16x8 kf1 = *(const bf16x8*)&Ks[(ni * 16 + lr) * 64 +
                                             (((4 + q) ^ (lr & 7)) * 8)];
            f32x4 z = {0.0f, 0.0f, 0.0f, 0.0f};
            z = __builtin_amdgcn_mfma_f32_16x16x32_bf16(kf0, qf[0], z, 0, 0, 0);
            z = __builtin_amdgcn_mfma_f32_16x16x32_bf16(kf1, qf[1], z, 0, 0, 0);
            st[ni] = z;
        }

        // additive mask + in-lane row max (lane owns 16 keys of q-row lr)
        float rmax = -1e30f;
#pragma unroll
        for (int ni = 0; ni < 4; ++ni) {
            float4 am = *(const float4*)&Amf[kv0 + ni * 16 + q * 4];
            st[ni][0] += am.x; st[ni][1] += am.y;
            st[ni][2] += am.z; st[ni][3] += am.w;
#pragma unroll
            for (int r = 0; r < 4; ++r) rmax = fmaxf(rmax, st[ni][r]);
        }
        rmax = fmaxf(rmax, __shfl_xor(rmax, 16));
        rmax = fmaxf(rmax, __shfl_xor(rmax, 32));

        // defer-max: only rescale when some row in the wave grew materially
        if (__any(rmax > mst + 11.5f)) {
            float mnew  = fmaxf(mst, rmax);
            float alpha = exp2_fast(mst - mnew);      // quad-uniform per row
            mst = mnew;
            lst *= alpha;
#pragma unroll
            for (int dj = 0; dj < 4; ++dj) {
                oacc[dj][0] *= alpha; oacc[dj][1] *= alpha;
                oacc[dj][2] *= alpha; oacc[dj][3] *= alpha;
            }
        }

        // P: logical elems [ni*16+q*4 .. +3] of row (w*16+lr); group
        // g = ni*2+(q>>1), sub-offset (q&1)*4; physical col (g^(lr&7))*8.
        float rsum = 0.0f;
#pragma unroll
        for (int ni = 0; ni < 4; ++ni) {
            float p0 = exp2_fast(st[ni][0] - mst);
            float p1 = exp2_fast(st[ni][1] - mst);
            float p2 = exp2_fast(st[ni][2] - mst);
            float p3 = exp2_fast(st[ni][3] - mst);
            rsum += (p0 + p1) + (p2 + p3);
            uint2 pw = make_uint2(cvtpk(p0, p1), cvtpk(p2, p3));
            *(uint2*)&QP[(w * 16 + lr) * 64 +
                         (((ni * 2 + (q >> 1)) ^ (lr & 7)) * 8) + (q & 1) * 4] = pw;
        }
        lst += rsum;                                  // lane-local; reduce later

        // O^T[d][q] += V^T · P^T  (wave-private P rows; DS in-order, no barrier)
#pragma unroll
        for (int ks = 0; ks < 2; ++ks) {
            bf16x8 pfB = *(const bf16x8*)&QP[(w * 16 + lr) * 64 +
                                             (((ks * 4 + q) ^ (lr & 7)) * 8)];
#pragma unroll
            for (int dj = 0; dj < 4; ++dj) {
                bf16x8 vfA = *(const bf16x8*)&Vs[(dj * 16 + lr) * 64 +
                                                 (((ks * 4 + q) ^ (lr & 7)) * 8)];
                oacc[dj] = __builtin_amdgcn_mfma_f32_16x16x32_bf16(vfA, pfB, oacc[dj], 0, 0, 0);
            }
        }
        __syncthreads();   // Ks/Vs free for next tile
    }

    // epilogue: reduce per-lane lst across the 4 quads of this q-row, then
    // O^T lane holds d = dj*16+q*4+r for q-row s = q0+w*16+lr
    {
        lst += __shfl_xor(lst, 16);
        lst += __shfl_xor(lst, 32);
        float inv = 1.0f / lst;
        int s = q0 + w * 16 + lr;
        uint16_t* xp = X + (size_t)(b * SS + s) * HIDN + h * DKK;
#pragma unroll
        for (int dj = 0; dj < 4; ++dj) {
            uint2 pw = make_uint2(cvtpk(oacc[dj][0] * inv, oacc[dj][1] * inv),
                                  cvtpk(oacc[dj][2] * inv, oacc[dj][3] * inv));
            *(uint2*)(xp + dj * 16 + q * 4) = pw;
        }
    }
}

extern "C" void kernel_launch(void* const* d_in, const int* in_sizes, int n_in,
                              void* d_out, int out_size, void* d_ws, size_t ws_size,
                              hipStream_t stream) {
    const float* query = (const float*)d_in[0];
    const float* key   = (const float*)d_in[1];
    const float* value = (const float*)d_in[2];
    const float* bias  = (const float*)d_in[3];
    const int*   mask  = (const int*)d_in[4];
    const float* wq = (const float*)d_in[5];
    const float* bq = (const float*)d_in[6];
    const float* wk = (const float*)d_in[7];
    const float* bk = (const float*)d_in[8];
    const float* wv = (const float*)d_in[9];
    const float* bv = (const float*)d_in[10];
    const float* wo = (const float*)d_in[11];
    const float* bo = (const float*)d_in[12];

    const size_t TEN = (size_t)NB * SS * HIDN;       // 4,194,304
    uint16_t* Qin = (uint16_t*)d_ws;                 // 0
    uint16_t* Kin = Qin + TEN;                       // 4M
    uint16_t* Vin = Kin + TEN;                       // 8M
    uint16_t* W16 = Vin + TEN;                       // 12M (4 x 1M: wq,wk,wv,wo)
    uint16_t* Qb  = W16 + 4 * 1048576;               // 16M
    uint16_t* Kb  = Qb + TEN;                        // 20M
    uint16_t* Vtb = Kb + TEN;                        // 24M (56 MB total)
    uint16_t* Xb  = Qin;                             // Qin dead after gemm_qkv

    cvt_all<<<4096, 256, 0, stream>>>(query, key, value, bias,
                                      wq, wk, wv, wo, Qin, Kin, Vin, W16);
    gemm_qkv<<<dim3(8, 32, 3), 256, 0, stream>>>(Qin, Kin, Vin, W16,
                                                 bq, bk, bv, Qb, Kb, Vtb);
    flash_attn<<<dim3(SS / 128, NB * NHEAD), 512, 0, stream>>>(Qb, Kb, Vtb, mask, Xb);
    gemm_out<<<dim3(8, 32), 256, 0, stream>>>(Xb, W16 + 3 * 1048576, bo, (float*)d_out);
}